// Round 1
// baseline (822.776 us; speedup 1.0000x reference)
//
#include <hip/hip_runtime.h>
#include <hip/hip_bf16.h>

typedef __attribute__((ext_vector_type(8))) short short8;
typedef __attribute__((ext_vector_type(4))) float f32x4;
typedef __hip_bfloat16 bf16;

#define MFMA16(a,b,c) __builtin_amdgcn_mfma_f32_16x16x32_bf16(a,b,c,0,0,0)

// B=4, T=1024, C=2048, NH=16, HS=128, NLQ=NLKV=512, DHR=64
// scale = 1/sqrt(192)

// ---------------- cast f32 -> bf16 (vectorized x4) ----------------
__global__ __launch_bounds__(256) void cast_bf16_kernel(const float* __restrict__ in,
                                                        bf16* __restrict__ out, long n4) {
  long i = (long)blockIdx.x * blockDim.x + threadIdx.x;
  if (i >= n4) return;
  float4 v = ((const float4*)in)[i];
  union { bf16 b[4]; uint2 u; } p;
  p.b[0] = __float2bfloat16(v.x);
  p.b[1] = __float2bfloat16(v.y);
  p.b[2] = __float2bfloat16(v.z);
  p.b[3] = __float2bfloat16(v.w);
  ((uint2*)out)[i] = p.u;
}

// ---------------- transpose f32 (R x C) -> bf16 (C x R) ----------------
__global__ void transpose_cast_kernel(const float* __restrict__ in, bf16* __restrict__ out,
                                      int R, int C) {
  __shared__ float t[32][33];
  int c0 = blockIdx.x * 32, r0 = blockIdx.y * 32;
  for (int j = threadIdx.y; j < 32; j += 8)
    t[j][threadIdx.x] = in[(long)(r0 + j) * C + c0 + threadIdx.x];
  __syncthreads();
  for (int j = threadIdx.y; j < 32; j += 8)
    out[(long)(c0 + j) * R + r0 + threadIdx.x] = __float2bfloat16(t[threadIdx.x][j]);
}

// ---------------- rope: in (BT, H, 64) f32 -> out bf16 same layout ----------------
__global__ __launch_bounds__(256) void rope_kernel(const float* __restrict__ in,
                                                   const float* __restrict__ cosT,
                                                   const float* __restrict__ sinT,
                                                   bf16* __restrict__ out, int H, long total) {
  long i = (long)blockIdx.x * blockDim.x + threadIdx.x;
  if (i >= total) return;
  int pair = (int)(i & 31);
  long rest = i >> 5;
  int h = (int)(rest % H);
  long bt = rest / H;
  int t = (int)(bt & 1023);
  long base = (bt * H + h) * 64 + pair * 2;
  float re = in[base], im = in[base + 1];
  float c = cosT[t * 32 + pair], s = sinT[t * 32 + pair];
  out[base] = __float2bfloat16(re * c - im * s);
  out[base + 1] = __float2bfloat16(re * s + im * c);
}

// ---------------- generic batched NT bf16 GEMM ----------------
// C[m,n] = sum_k A[m,k]*B[n,k]; A,B bf16 row-major with ld; C f32 or bf16.
// batch offsets: ((z/adiv)%amod)*astr elements for A, likewise B; C: z*cstr.
template <int OUT_BF16>
__global__ __launch_bounds__(256) void gemm_nt(const bf16* __restrict__ A,
                                               const bf16* __restrict__ B,
                                               void* __restrict__ Cv, int M, int N, int K,
                                               int lda, int ldb, int ldc,
                                               int adiv, int amod, long astr,
                                               int bdiv, int bmod, long bstr, long cstr) {
  __shared__ bf16 As[128][40];
  __shared__ bf16 Bs[128][40];
  const int tid = threadIdx.x;
  const int lane = tid & 63;
  const int w = tid >> 6;
  const int wr = w >> 1, wc = w & 1;
  const int z = blockIdx.z;
  A += ((long)((z / adiv) % amod)) * astr;
  B += ((long)((z / bdiv) % bmod)) * bstr;
  const int m0 = blockIdx.x * 128, n0 = blockIdx.y * 128;
  const int l16 = lane & 15, lg = lane >> 4;
  f32x4 acc[4][4] = {};
  for (int k0 = 0; k0 < K; k0 += 32) {
    for (int j = 0; j < 2; ++j) {
      int chunk = tid + 256 * j;        // 0..511
      int row = chunk >> 2, c8 = (chunk & 3) * 8;
      int4 va = *(const int4*)(A + (long)(m0 + row) * lda + k0 + c8);
      *(int4*)(&As[row][c8]) = va;
      int4 vb;
      if (n0 + row < N) vb = *(const int4*)(B + (long)(n0 + row) * ldb + k0 + c8);
      else vb = int4{0, 0, 0, 0};
      *(int4*)(&Bs[row][c8]) = vb;
    }
    __syncthreads();
    short8 af[4], bfr[4];
    for (int i = 0; i < 4; ++i) {
      af[i] = *(const short8*)(&As[wr * 64 + i * 16 + l16][lg * 8]);
      bfr[i] = *(const short8*)(&Bs[wc * 64 + i * 16 + l16][lg * 8]);
    }
    for (int i = 0; i < 4; ++i)
      for (int j2 = 0; j2 < 4; ++j2) acc[i][j2] = MFMA16(af[i], bfr[j2], acc[i][j2]);
    __syncthreads();
  }
  for (int i = 0; i < 4; ++i)
    for (int j2 = 0; j2 < 4; ++j2) {
      int col = n0 + wc * 64 + j2 * 16 + l16;
      if (col >= N) continue;
      long rbase = (long)(m0 + wr * 64 + i * 16 + lg * 4);
      for (int r = 0; r < 4; ++r) {
        float v = acc[i][j2][r];
        long idx = (long)z * cstr + (rbase + r) * ldc + col;
        if (OUT_BF16) ((bf16*)Cv)[idx] = __float2bfloat16(v);
        else ((float*)Cv)[idx] = v;
      }
    }
}

// ---------------- flash attention ----------------
// grid (T/64, NH, B), block 256 (4 waves). Wave w owns Q rows t0+w*16..+16.
// Q dims 576 = q_c(512) ++ q_r(64). K from c_kv ++ k_r staged in LDS.
// V = vT (B,NH,128,T) staged in LDS. Online softmax (log2 domain).
__global__ __launch_bounds__(256) void attn_kernel(const bf16* __restrict__ q_c,  // (B,NH,T,512)
                                                   const bf16* __restrict__ q_r,  // (B,T,NH,64)
                                                   const bf16* __restrict__ kc,   // (B,T,512)
                                                   const bf16* __restrict__ kr,   // (B,T,64)
                                                   const bf16* __restrict__ vT,   // (B,NH,128,T)
                                                   float* __restrict__ out) {     // (B,T,2048)
  const int qb = blockIdx.x, h = blockIdx.y, b = blockIdx.z;
  const int t0 = qb * 64;
  const int tid = threadIdx.x, lane = tid & 63, w = tid >> 6;
  const int l16 = lane & 15, lg = lane >> 4;
  __shared__ bf16 Klds[32][584];   // 32 keys x 576 (+8 pad)
  __shared__ bf16 Vlds[128][40];   // 128 dims x 32 keys (+8 pad)
  __shared__ bf16 Plds[4][16][40]; // per-wave P bounce

  short8 aq[18];
  {
    const int trow = t0 + w * 16 + l16;
    const bf16* qcp = q_c + ((long)(b * 16 + h) * 1024 + trow) * 512;
    for (int kk = 0; kk < 16; ++kk) aq[kk] = *(const short8*)(qcp + kk * 32 + lg * 8);
    const bf16* qrp = q_r + (((long)b * 1024 + trow) * 16 + h) * 64;
    aq[16] = *(const short8*)(qrp + lg * 8);
    aq[17] = *(const short8*)(qrp + 32 + lg * 8);
  }
  f32x4 oacc[8] = {};
  float m_run[4], l_run[4];
  for (int r = 0; r < 4; ++r) { m_run[r] = -1e30f; l_run[r] = 0.f; }
  const int nkb = (t0 + 64) >> 5;
  const float sc = 0.0721687836f * 1.44269504f;  // (1/sqrt(192)) * log2(e)

  for (int kb = 0; kb < nkb; ++kb) {
    const int s0 = kb * 32;
    __syncthreads();
    for (int j = 0; j < 9; ++j) {  // K tile: 32 rows x 576 = 2304 16B-chunks
      int chunk = tid + 256 * j;
      int row = chunk / 72, c = chunk % 72;
      int4 v;
      if (c < 64) v = *(const int4*)(kc + ((long)b * 1024 + s0 + row) * 512 + c * 8);
      else        v = *(const int4*)(kr + ((long)b * 1024 + s0 + row) * 64 + (c - 64) * 8);
      *(int4*)(&Klds[row][c * 8]) = v;
    }
    for (int j = 0; j < 2; ++j) {  // V tile: 128 rows x 32
      int chunk = tid + 256 * j;
      int row = chunk >> 2, c = (chunk & 3) * 8;
      int4 v = *(const int4*)(vT + ((long)(b * 16 + h) * 128 + row) * 1024 + s0 + c);
      *(int4*)(&Vlds[row][c]) = v;
    }
    __syncthreads();

    f32x4 s_acc[2] = {};
    for (int kk = 0; kk < 18; ++kk) {
      short8 b0 = *(const short8*)(&Klds[l16][kk * 32 + lg * 8]);
      short8 b1 = *(const short8*)(&Klds[16 + l16][kk * 32 + lg * 8]);
      s_acc[0] = MFMA16(aq[kk], b0, s_acc[0]);
      s_acc[1] = MFMA16(aq[kk], b1, s_acc[1]);
    }
    float p[2][4], rmax[4];
    for (int r = 0; r < 4; ++r) {
      int tg = t0 + w * 16 + lg * 4 + r;
      float s0v = s_acc[0][r] * sc, s1v = s_acc[1][r] * sc;
      if (s0 + l16 > tg) s0v = -1e30f;
      if (s0 + 16 + l16 > tg) s1v = -1e30f;
      p[0][r] = s0v; p[1][r] = s1v;
      float mx = fmaxf(s0v, s1v);
      mx = fmaxf(mx, __shfl_xor(mx, 1));
      mx = fmaxf(mx, __shfl_xor(mx, 2));
      mx = fmaxf(mx, __shfl_xor(mx, 4));
      mx = fmaxf(mx, __shfl_xor(mx, 8));
      rmax[r] = mx;
    }
    float alpha[4];
    for (int r = 0; r < 4; ++r) {
      float mnew = fmaxf(m_run[r], rmax[r]);
      alpha[r] = exp2f(m_run[r] - mnew);
      m_run[r] = mnew;
      float p0 = exp2f(p[0][r] - mnew);
      float p1 = exp2f(p[1][r] - mnew);
      p[0][r] = p0; p[1][r] = p1;
      float rs = p0 + p1;
      rs += __shfl_xor(rs, 1);
      rs += __shfl_xor(rs, 2);
      rs += __shfl_xor(rs, 4);
      rs += __shfl_xor(rs, 8);
      l_run[r] = l_run[r] * alpha[r] + rs;
    }
    for (int f = 0; f < 8; ++f)
      for (int r = 0; r < 4; ++r) oacc[f][r] *= alpha[r];
    for (int nf = 0; nf < 2; ++nf)
      for (int r = 0; r < 4; ++r)
        Plds[w][lg * 4 + r][nf * 16 + l16] = __float2bfloat16(p[nf][r]);
    // same-wave DS ops are in-order; read-back is safe without barrier
    short8 pa = *(const short8*)(&Plds[w][l16][lg * 8]);
    for (int f = 0; f < 8; ++f) {
      short8 vb = *(const short8*)(&Vlds[f * 16 + l16][lg * 8]);
      oacc[f] = MFMA16(pa, vb, oacc[f]);
    }
  }
  for (int f = 0; f < 8; ++f)
    for (int r = 0; r < 4; ++r) {
      int t = t0 + w * 16 + lg * 4 + r;
      int col = f * 16 + l16;
      out[((long)(b * 1024 + t)) * 2048 + h * 128 + col] = oacc[f][r] / l_run[r];
    }
}

extern "C" void kernel_launch(void* const* d_in, const int* in_sizes, int n_in, void* d_out,
                              int out_size, void* d_ws, size_t ws_size, hipStream_t stream) {
  const float* x = (const float*)d_in[0];
  const float* W_dq = (const float*)d_in[1];
  const float* W_uq = (const float*)d_in[2];
  const float* W_dkv = (const float*)d_in[3];
  const float* W_uk = (const float*)d_in[4];
  const float* W_uv = (const float*)d_in[5];
  const float* W_o = (const float*)d_in[6];
  const float* W_qr = (const float*)d_in[7];
  const float* W_kr = (const float*)d_in[8];
  const float* fcos = (const float*)d_in[9];
  const float* fsin = (const float*)d_in[10];
  float* out = (float*)d_out;

  char* p = (char*)d_ws;
  auto alloc = [&](long bytes) { void* r = p; p += (bytes + 255) & ~255L; return r; };
  bf16* xb = (bf16*)alloc(8388608L * 2);        // (4096,2048)
  bf16* Wdq_b = (bf16*)alloc(1048576L * 2);     // (512,2048)
  bf16* Wdkv_b = (bf16*)alloc(1048576L * 2);    // (512,2048)
  bf16* Wkr_b = (bf16*)alloc(131072L * 2);      // (64,2048)
  bf16* Wqr_b = (bf16*)alloc(524288L * 2);      // (1024,512)
  bf16* Wo_b = (bf16*)alloc(4194304L * 2);      // (2048,2048)
  bf16* Wuq_b = (bf16*)alloc(1048576L * 2);     // flat (512q,16h,128d) strides (2048,128,1)
  bf16* WukT_b = (bf16*)alloc(1048576L * 2);    // (512,2048) = W_uk^T
  bf16* WuvT_b = (bf16*)alloc(1048576L * 2);    // (512,2048) = W_uv^T
  bf16* c_q_b = (bf16*)alloc(2097152L * 2);     // (4096,512)
  bf16* c_kv_b = (bf16*)alloc(2097152L * 2);    // (4096,512)
  bf16* kefT_b = (bf16*)alloc(4194304L * 2);    // (16,512,512) k_eff^T per head
  bf16* veffT_b = (bf16*)alloc(1048576L * 2);   // (2048,512)
  bf16* q_c = (bf16*)alloc(33554432L * 2);      // (4,16,1024,512)
  float* c_qr_f = (float*)alloc(4194304L * 4);  // (4096,1024)
  bf16* q_r_b = (bf16*)alloc(4194304L * 2);     // (4,1024,16,64)
  float* c_kr_f = (float*)alloc(262144L * 4);   // (4096,64)
  bf16* k_r_b = (bf16*)alloc(262144L * 2);      // (4,1024,64)
  bf16* vT_b = (bf16*)alloc(8388608L * 2);      // (4,16,128,1024)

  // casts
  cast_bf16_kernel<<<8192, 256, 0, stream>>>(x, xb, 2097152);
  cast_bf16_kernel<<<1024, 256, 0, stream>>>(W_dq, Wdq_b, 262144);
  cast_bf16_kernel<<<1024, 256, 0, stream>>>(W_dkv, Wdkv_b, 262144);
  cast_bf16_kernel<<<128, 256, 0, stream>>>(W_kr, Wkr_b, 32768);
  cast_bf16_kernel<<<512, 256, 0, stream>>>(W_qr, Wqr_b, 131072);
  cast_bf16_kernel<<<4096, 256, 0, stream>>>(W_o, Wo_b, 1048576);
  cast_bf16_kernel<<<1024, 256, 0, stream>>>(W_uq, Wuq_b, 262144);
  transpose_cast_kernel<<<dim3(16, 64), dim3(32, 8), 0, stream>>>(W_uk, WukT_b, 2048, 512);
  transpose_cast_kernel<<<dim3(16, 64), dim3(32, 8), 0, stream>>>(W_uv, WuvT_b, 2048, 512);

  // c_q = x @ W_dq^T   (4096,512,2048)
  gemm_nt<1><<<dim3(32, 4, 1), 256, 0, stream>>>(xb, Wdq_b, c_q_b, 4096, 512, 2048, 2048, 2048,
                                                 512, 1, 1, 0, 1, 1, 0, 0);
  // c_kv = x @ W_dkv^T
  gemm_nt<1><<<dim3(32, 4, 1), 256, 0, stream>>>(xb, Wdkv_b, c_kv_b, 4096, 512, 2048, 2048, 2048,
                                                 512, 1, 1, 0, 1, 1, 0, 0);
  // c_kr = x @ W_kr^T  (f32 out)
  gemm_nt<0><<<dim3(32, 1, 1), 256, 0, stream>>>(xb, Wkr_b, c_kr_f, 4096, 64, 2048, 2048, 2048,
                                                 64, 1, 1, 0, 1, 1, 0, 0);
  // kefT[h](k,q) = sum_d WukT[k, h*128+d] * Wuq[q*2048 + h*128 + d]
  gemm_nt<1><<<dim3(4, 4, 16), 256, 0, stream>>>(WukT_b, Wuq_b, kefT_b, 512, 512, 128, 2048, 2048,
                                                 512, 1, 16, 128, 1, 16, 128, 262144);
  // veffT[d,k] = sum_c W_o[d,c] * W_uv[c,k]
  gemm_nt<1><<<dim3(16, 4, 1), 256, 0, stream>>>(Wo_b, WuvT_b, veffT_b, 2048, 512, 2048, 2048,
                                                 2048, 512, 1, 1, 0, 1, 1, 0, 0);
  // c_qr = c_q @ W_qr^T (f32 out)
  gemm_nt<0><<<dim3(32, 8, 1), 256, 0, stream>>>(c_q_b, Wqr_b, c_qr_f, 4096, 1024, 512, 512, 512,
                                                 1024, 1, 1, 0, 1, 1, 0, 0);
  // q_c[b,h] = c_q[b] @ kefT[h]^T  (z = b*16+h)
  gemm_nt<1><<<dim3(8, 4, 64), 256, 0, stream>>>(c_q_b, kefT_b, q_c, 1024, 512, 512, 512, 512,
                                                 512, 16, 4, 524288, 1, 16, 262144, 524288);
  // vT[b,h](d,s) = sum_k veffT[h*128+d,k] * c_kv[b,s,k]
  gemm_nt<1><<<dim3(1, 8, 64), 256, 0, stream>>>(veffT_b, c_kv_b, vT_b, 128, 1024, 512, 512, 512,
                                                 1024, 1, 16, 65536, 16, 4, 524288, 131072);
  // rope
  rope_kernel<<<8192, 256, 0, stream>>>(c_qr_f, fcos, fsin, q_r_b, 16, 2097152);
  rope_kernel<<<512, 256, 0, stream>>>(c_kr_f, fcos, fsin, k_r_b, 1, 131072);
  // attention
  attn_kernel<<<dim3(16, 16, 4), 256, 0, stream>>>(q_c, q_r_b, c_kv_b, k_r_b, vT_b, out);
}